// Round 8
// baseline (524.145 us; speedup 1.0000x reference)
//
#include <hip/hip_runtime.h>
#include <hip/hip_bf16.h>

typedef __attribute__((ext_vector_type(8))) short short8;
typedef __attribute__((ext_vector_type(4))) float floatx4;
typedef __attribute__((ext_vector_type(16))) float floatx16;
typedef unsigned short u16;
typedef unsigned int u32;

#define BATCH 16
#define HH 224
#define WW 224
#define ICN 64
#define OCN 128
#define HP 226
#define WP 226

// conv tile: 4 output rows x 40 cols per WG (6 w-chunks; last overlaps, stores idempotent)
#define MTT 160           // output px per block
#define AR6 252           // 6 padded input rows x 42 padded cols
#define A6_BYTES (AR6*128) // 32256
#define AQ6 (AR6*8)       // 2016 16-B chunks

#define NPX (BATCH*113*4)  // 7232 prep_x blocks; +288 prep_w tail blocks

#define XB_BYTES ((size_t)BATCH*HP*WP*ICN*2)   // 104,603,648
#define WB_BYTES ((size_t)OCN*ICN*9*2)         // 147,456

// async global->LDS, 16B per lane; LDS dest = wave-uniform base + lane*16
#define ASYNC16(g, l) __builtin_amdgcn_global_load_lds( \
    (const __attribute__((address_space(1))) void*)(g), \
    (__attribute__((address_space(3))) void*)(l), 16, 0, 0)

__device__ __forceinline__ u16 f2bf(float f) {
  __hip_bfloat16 h = __float2bfloat16(f);
  return *reinterpret_cast<u16*>(&h);
}

__device__ __forceinline__ float fast_tanh(float x) {
  float e = __expf(2.0f * x);    // x>>0 -> 1, x<<0 -> -1, inf-safe
  return 1.0f - 2.0f / (e + 1.0f);
}

// ---------- inline container-dtype detect (verified R3) ----------
__device__ __forceinline__ bool detect_isbf(const u32* __restrict__ xw, int tid) {
  u32 w = xw[tid & 63];
  int e0 = (w >> 7) & 0xFF;
  int e1 = (w >> 23) & 0xFF;
  unsigned long long b0 = __ballot(e0 >= 90 && e0 <= 160);
  unsigned long long b1 = __ballot(e1 >= 90 && e1 <= 160);
  return (__popcll(b0) + __popcll(b1)) >= 120;
}

// ---------- prep_all (VERBATIM, verified R3/R6): prep_x + prep_w tail ----------
__global__ __launch_bounds__(256) void prep_all(const void* __restrict__ xv,
                                                const void* __restrict__ wv_,
                                                u16* __restrict__ xb,
                                                u16* __restrict__ wb) {
  __shared__ u32 tile32[2][64*33];   // [w_local][ic_pair], stride 33
  const int tid = threadIdx.x;
  const bool isbf = detect_isbf((const u32*)xv, tid);
  int bid = blockIdx.x;

  if (bid >= NPX) {                  // ---- prep_w tail ----
    int o = (bid - NPX)*256 + tid;   // 0..73727
    int oc = o / 576;
    int k = o - oc*576;
    int tap = k >> 6;
    int ic = k & 63;
    int src = oc*576 + ic*9 + tap;
    wb[o] = isbf ? ((const u16*)wv_)[src] : f2bf(((const float*)wv_)[src]);
    return;
  }

  const int chunk = bid & 3;         // 4 chunks of 64 input cols
  int rest = bid >> 2;
  const int hp0 = rest % 113;        // rows hp0 and hp0+113
  const int b = rest / 113;
  const int wt = chunk * 64;
  const int icp = tid >> 3;          // ic pair 0..31
  const int oct = tid & 7;           // w octet 0..7
  const int w = wt + oct*8;
  const int ic0 = icp*2;

  #pragma unroll
  for (int t = 0; t < 2; ++t) {
    const int hp = hp0 + t*113;
    const int h = hp - 1;
    const bool valid = (h >= 0) && (h < HH) && (w < WW);
    const size_t b0 = (((size_t)(b*ICN + ic0))*HH + h)*WW + w;
    const size_t b1 = (((size_t)(b*ICN + ic0+1))*HH + h)*WW + w;
    u16 a[8], c[8];
    if (isbf) {
      short8 v0 = {0,0,0,0,0,0,0,0}, v1 = {0,0,0,0,0,0,0,0};
      if (valid) {
        v0 = *(const short8*)((const u16*)xv + b0);
        v1 = *(const short8*)((const u16*)xv + b1);
      }
      #pragma unroll
      for (int s = 0; s < 8; ++s) { a[s] = (u16)v0[s]; c[s] = (u16)v1[s]; }
    } else {
      floatx4 f0={0,0,0,0}, f1={0,0,0,0}, f2={0,0,0,0}, f3={0,0,0,0};
      if (valid) {
        const float* p0 = (const float*)xv + b0;
        const float* p1 = (const float*)xv + b1;
        f0 = *(const floatx4*)p0; f1 = *(const floatx4*)(p0+4);
        f2 = *(const floatx4*)p1; f3 = *(const floatx4*)(p1+4);
      }
      #pragma unroll
      for (int s = 0; s < 4; ++s) {
        a[s] = f2bf(f0[s]); a[4+s] = f2bf(f1[s]);
        c[s] = f2bf(f2[s]); c[4+s] = f2bf(f3[s]);
      }
    }
    #pragma unroll
    for (int s = 0; s < 8; ++s)
      tile32[t][(oct*8 + s)*33 + icp] = (u32)a[s] | ((u32)c[s] << 16);
  }
  __syncthreads();
  #pragma unroll
  for (int t = 0; t < 2; ++t) {
    const int hp = hp0 + t*113;
    #pragma unroll
    for (int p = 0; p < 2; ++p) {
      int idx = p*256 + tid;
      int wl = idx >> 3;
      int icc = idx & 7;
      int wp = wt + 1 + wl;
      if (wp < WP) {
        u32 cc[4];
        #pragma unroll
        for (int j = 0; j < 4; ++j) cc[j] = tile32[t][wl*33 + icc*4 + j];
        short8 o;
        #pragma unroll
        for (int j = 0; j < 4; ++j) { o[2*j] = (short)(cc[j] & 0xFFFF); o[2*j+1] = (short)(cc[j] >> 16); }
        *(short8*)(xb + (((size_t)(b*HP) + hp)*WP + wp)*ICN + icc*8) = o;
      }
    }
    if (chunk == 0 && tid < 8) {     // left border column wp=0
      short8 z = {0,0,0,0,0,0,0,0};
      *(short8*)(xb + (((size_t)(b*HP) + hp)*WP)*ICN + tid*8) = z;
    }
  }
}

// ---------- fused conv3x3 + bias + min_oc + double tanh (32x32x16 MFMA) ----------
// R6 finding: duration tracks MFMA INSTRUCTION count (~17 cy/instr effective) with
// no throughput counter near ceiling -> halve instruction count at equal FLOPs.
// Per wave: 5 m-tiles (32 px) x 1 oc-tile (32 oc, = wave id) x 36 K-steps of 16.
// Operand layouts (extrapolated from the verified 16x16 pattern; C/D HW-verified):
//   A: lane l -> row (pixel) = l&31, k = (l>>5)*8 + j  (one b128 from LDS)
//   B: lane l -> col (oc)    = l&31, k = (l>>5)*8 + j  (one short8 from wb)
//   D: col (oc) = l&31, row (px-in-tile) = (r&3) + 8*(r>>2) + 4*(l>>5), r=0..15
// Staging (ASYNC16 + involution slot^(r&7)) and tile geometry VERBATIM from R6.
// A-read is inherently 4-way bank-conflicted (32 rows -> 8 slots); budgeted.
__global__ __launch_bounds__(256, 2) void conv_min_kernel(
    const u16* __restrict__ xb, const u16* __restrict__ wb,
    const void* __restrict__ biasv, void* __restrict__ outv,
    const void* __restrict__ xv)
{
  __shared__ __align__(16) char ldsA[A6_BYTES];  // 252 rows x 128 B
  float* minbuf = (float*)ldsA;                  // aliased post-loop (barrier-fenced)

  const int tid = threadIdx.x;
  const bool isbf = detect_isbf((const u32*)xv, tid);
  const int wv = tid >> 6;           // wave = oc-tile: oc in [wv*32, wv*32+32)
  const int lane = tid & 63;
  const int l31 = lane & 31;
  const int lhi = lane >> 5;         // k-half selector

  int bid = blockIdx.x;
  const int wsel = bid % 6;
  int rest = bid / 6;
  const int h0 = (rest % 56) * 4;    // 4 output rows h0..h0+3
  const int b = rest / 56;
  const int w0 = (wsel < 5) ? wsel*40 : 184;     // last chunk overlaps; stores idempotent

  // ---- stage A via async global->LDS (VERBATIM R6): 2016 chunks, q = it*256+tid
  const char* srcb = (const char*)xb + 2*((((size_t)(b*HP) + h0)*WP)*ICN) + (size_t)w0*128;
  #pragma unroll
  for (int it = 0; it < 8; ++it) {
    if (it < 7 || tid < 224) {       // AQ6 = 2016 = 7*256 + 224
      int q = it*256 + tid;
      int r = q >> 3;
      int slot = q & 7;
      int c = slot ^ (r & 7);
      int dyi = (r * 781) >> 15;     // r/42, exact for r < 252
      int wloc = r - dyi*42;
      int off = ((dyi*WP + wloc)*ICN + c*8) * 2;
      ASYNC16(srcb + off, ldsA + it*4096 + wv*1024);
    }
  }

  // ---- per-lane A-row bases: pixel p = mt*32 + l31 -> (p/40)*42 + p%40
  int arow[5];
  #pragma unroll
  for (int mt = 0; mt < 5; ++mt) {
    int pp = mt*32 + l31;
    int ro = pp / 40;
    arow[mt] = ro*42 + (pp - ro*40);
  }

  // ---- per-lane B: oc = wv*32 + l31; element = oc*576 + tap*64 + ksl*16 + lhi*8 + j
  const u16* bbase = wb + (wv*32 + l31)*576 + lhi*8;
  short8 bcur[4];
  #pragma unroll
  for (int ksl = 0; ksl < 4; ++ksl)
    bcur[ksl] = *(const short8*)(bbase + ksl*16);

  floatx16 acc[5];
  const floatx16 zz = {0.f,0.f,0.f,0.f,0.f,0.f,0.f,0.f,0.f,0.f,0.f,0.f,0.f,0.f,0.f,0.f};
  #pragma unroll
  for (int mt = 0; mt < 5; ++mt) acc[mt] = zz;

  __syncthreads();                         // drains vmcnt -> A resident

  #pragma unroll
  for (int tap = 0; tap < 9; ++tap) {
    short8 bnxt[4];
    if (tap < 8) {                         // prefetch next tap's B frags (L1/L2-hit)
      #pragma unroll
      for (int ksl = 0; ksl < 4; ++ksl)
        bnxt[ksl] = *(const short8*)(bbase + (tap+1)*64 + ksl*16);
    }
    const int dy = tap / 3;
    const int dx = tap - dy*3;
    const int rdelta = dy*42 + dx;
    #pragma unroll
    for (int ksl = 0; ksl < 4; ++ksl) {    // 4 K=16 steps per tap (64 ic)
      const int cp = ksl*2 + lhi;          // 16-B chunk index within row
      short8 af[5];
      #pragma unroll
      for (int mt = 0; mt < 5; ++mt) {
        int row = arow[mt] + rdelta;
        af[mt] = *(const short8*)(ldsA + row*128 + ((cp ^ (row & 7))*16));
      }
      #pragma unroll
      for (int mt = 0; mt < 5; ++mt)
        acc[mt] = __builtin_amdgcn_mfma_f32_32x32x16_bf16(af[mt], bcur[ksl], acc[mt], 0, 0, 0);
    }
    if (tap < 8) {
      #pragma unroll
      for (int ksl = 0; ksl < 4; ++ksl)
        bcur[ksl] = bnxt[ksl];
    }
  }
  __syncthreads();   // fence A reads before minbuf aliasing writes

  // ---- epilogue: +bias, min over this wave's 32 oc (lanes l31), cross-wave via
  //      minbuf (4 oc-tiles), tanh(tanh), store
  const float bv = isbf ? __bfloat162float(((const __hip_bfloat16*)biasv)[wv*32 + l31])
                        : ((const float*)biasv)[wv*32 + l31];
  #pragma unroll
  for (int mt = 0; mt < 5; ++mt) {
    #pragma unroll
    for (int r = 0; r < 16; ++r) {
      float v = acc[mt][r] + bv;
      v = fminf(v, __shfl_xor(v, 1));
      v = fminf(v, __shfl_xor(v, 2));
      v = fminf(v, __shfl_xor(v, 4));
      v = fminf(v, __shfl_xor(v, 8));
      v = fminf(v, __shfl_xor(v, 16));
      if (l31 == 0)    // lanes 0 and 32 hold mins for px-in-tile ...+0 / ...+4
        minbuf[wv*MTT + mt*32 + (r & 3) + 8*(r >> 2) + 4*lhi] = v;
    }
  }
  __syncthreads();
  if (tid < MTT) {
    float v = fminf(fminf(minbuf[tid], minbuf[MTT + tid]),
                    fminf(minbuf[2*MTT + tid], minbuf[3*MTT + tid]));
    float t = fast_tanh(fast_tanh(v));
    int ro = tid / 40;
    int co = tid - ro*40;
    size_t oi = ((size_t)(b*HH + h0 + ro))*WW + w0 + co;
    if (isbf) ((__hip_bfloat16*)outv)[oi] = __float2bfloat16(t);
    else      ((float*)outv)[oi] = t;
  }
}

extern "C" void kernel_launch(void* const* d_in, const int* in_sizes, int n_in,
                              void* d_out, int out_size, void* d_ws, size_t ws_size,
                              hipStream_t stream) {
  (void)in_sizes; (void)n_in; (void)out_size;
  if (ws_size < XB_BYTES + WB_BYTES + 16) return;

  const void* x  = d_in[0];
  const void* w  = d_in[1];
  const void* bias = d_in[2];
  u16* xb = (u16*)d_ws;
  u16* wb = (u16*)((char*)d_ws + XB_BYTES);

  prep_all<<<NPX + 288, 256, 0, stream>>>(x, w, xb, wb);
  conv_min_kernel<<<6*56*BATCH, 256, 0, stream>>>(xb, wb, bias, d_out, x);
}